// Round 1
// baseline (134.590 us; speedup 1.0000x reference)
//
#include <hip/hip_runtime.h>
#include <hip/hip_bf16.h>
#include <math.h>

#define NN 8192
#define CC 256
#define OO 64
#define NCH 32

// Kernel 1: seq[i][o] = x[i,:]@W1[o,:] + b1[o] ; f1[i]=seq[i,:]@a1+ba1 ; f2 likewise; exp tables
__global__ __launch_bounds__(256) void k_seq(
    const float* __restrict__ x, const float* __restrict__ W1,
    const float* __restrict__ b1, const float* __restrict__ a1,
    const float* __restrict__ ba1, const float* __restrict__ a2,
    const float* __restrict__ ba2,
    float* __restrict__ seq, float* __restrict__ f1, float* __restrict__ f2,
    float* __restrict__ E1, float* __restrict__ E1s,
    float* __restrict__ eF2, float* __restrict__ eF2s)
{
  const int tid = threadIdx.x;
  const int og = tid & 15;          // 16 column groups, o = og + 16k
  const int row = tid >> 4;         // 16 rows per block
  const int i = blockIdx.x * 16 + row;
  const float* xr = x + (size_t)i * CC;
  float acc[4];
#pragma unroll
  for (int k = 0; k < 4; ++k) acc[k] = b1[og + 16*k];
  for (int c = 0; c < CC; c += 4) {
    const float4 xv = *(const float4*)(xr + c);
#pragma unroll
    for (int k = 0; k < 4; ++k) {
      const float4 wv = *(const float4*)(W1 + (og + 16*k)*CC + c);
      acc[k] = fmaf(xv.x, wv.x, acc[k]);
      acc[k] = fmaf(xv.y, wv.y, acc[k]);
      acc[k] = fmaf(xv.z, wv.z, acc[k]);
      acc[k] = fmaf(xv.w, wv.w, acc[k]);
    }
  }
  float p1 = 0.f, p2 = 0.f;
#pragma unroll
  for (int k = 0; k < 4; ++k) {
    const int o = og + 16*k;
    seq[(size_t)i*OO + o] = acc[k];
    p1 = fmaf(acc[k], a1[o], p1);
    p2 = fmaf(acc[k], a2[o], p2);
  }
  __shared__ float s1[16][17], s2[16][17];
  s1[row][og] = p1; s2[row][og] = p2;
  __syncthreads();
  if (og == 0) {
    float t1 = 0.f, t2 = 0.f;
    for (int q = 0; q < 16; ++q) { t1 += s1[row][q]; t2 += s2[row][q]; }
    t1 += ba1[0]; t2 += ba2[0];
    f1[i] = t1; E1[i] = expf(t1); E1s[i] = expf(0.01f*t1);
    f2[i] = t2; eF2[i] = expf(t2); eF2s[i] = expf(0.01f*t2);
  }
}

// Kernel 2: per j, over one i-chunk: partial softmax-denominator terms + partial rank of f2[j]
__global__ __launch_bounds__(256) void k_part(
    const float* __restrict__ f1, const float* __restrict__ f2,
    const float* __restrict__ E1, const float* __restrict__ E1s,
    float* __restrict__ pA, float* __restrict__ pB, float* __restrict__ pR)
{
  const int ch = blockIdx.x >> 5;        // 32 i-chunks of 256
  const int jb = blockIdx.x & 31;        // 32 j-blocks of 256
  const int j = jb*256 + threadIdx.x;
  __shared__ float sf1[256], sa[256], sb[256], sf2c[256];
  const int ib = ch*256;
  sf1[threadIdx.x]  = f1[ib + threadIdx.x];
  sa[threadIdx.x]   = E1[ib + threadIdx.x];
  sb[threadIdx.x]   = E1s[ib + threadIdx.x];
  sf2c[threadIdx.x] = f2[ib + threadIdx.x];
  __syncthreads();
  const float myf2 = f2[j];
  const float t = -myf2;
  float accA = 0.f, accB = 0.f, cnt = 0.f;
#pragma unroll 4
  for (int ii = 0; ii < 256; ++ii) {
    const bool ge = sf1[ii] >= t;          // f1[i]+f2[j] >= 0
    accA += ge ? sa[ii] : 0.f;
    accB += ge ? 0.f : sb[ii];
    const float w = sf2c[ii];
    cnt += (w < myf2 || (w == myf2 && (ib+ii) < j)) ? 1.f : 0.f;
  }
  pA[ch*NN + j] = accA;
  pB[ch*NN + j] = accB;
  pR[ch*NN + j] = cnt;
}

// Kernel 3: reduce partials -> D_j, scale factors, rank; scatter sorted f2
__global__ __launch_bounds__(256) void k_reduce(
    const float* __restrict__ pA, const float* __restrict__ pB,
    const float* __restrict__ pR, const float* __restrict__ f2,
    const float* __restrict__ eF2, const float* __restrict__ eF2s,
    float* __restrict__ Bfac, float* __restrict__ Efac,
    int* __restrict__ rank, float* __restrict__ f2s)
{
  const int j = blockIdx.x*256 + threadIdx.x;
  float A = 0.f, Bv = 0.f, R = 0.f;
  for (int ch = 0; ch < NCH; ++ch) {
    A  += pA[ch*NN + j];
    Bv += pB[ch*NN + j];
    R  += pR[ch*NN + j];
  }
  const float D = A*eF2[j] + Bv*eF2s[j];
  Bfac[j] = eF2[j]/D;
  Efac[j] = eF2s[j]/D;
  const int r = (int)(R + 0.5f);
  rank[j] = r;
  f2s[r] = f2[j];
}

// Kernel 4: scatter u,v into sorted-by-f2 order
__global__ __launch_bounds__(256) void k_scatter(
    const float* __restrict__ seq, const int* __restrict__ rank,
    const float* __restrict__ Bfac, const float* __restrict__ Efac,
    float* __restrict__ u_s, float* __restrict__ v_s)
{
  const int gid = blockIdx.x*256 + threadIdx.x;
  const int j = gid >> 6, o = gid & 63;
  const int r = rank[j];
  const float s = seq[(size_t)j*OO + o];
  u_s[(size_t)r*OO + o] = Bfac[j]*s;
  v_s[(size_t)r*OO + o] = Efac[j]*s;
}

// Kernel 5: per-chunk column totals (chunk = 256 sorted rows)
__global__ __launch_bounds__(256) void k_sumchunk(
    const float* __restrict__ u_s, const float* __restrict__ v_s,
    float* __restrict__ TU, float* __restrict__ TV)
{
  const int b = blockIdx.x, tid = threadIdx.x;
  const int ks = tid >> 6, o = tid & 63;
  float su = 0.f, sv = 0.f;
  for (int m = 0; m < 64; ++m) {
    const size_t idx = ((size_t)(b*256 + ks*64 + m))*OO + o;
    su += u_s[idx]; sv += v_s[idx];
  }
  __shared__ float lu[4][64], lv[4][64];
  lu[ks][o] = su; lv[ks][o] = sv;
  __syncthreads();
  if (ks == 0) {
    TU[b*64+o] = lu[0][o]+lu[1][o]+lu[2][o]+lu[3][o];
    TV[b*64+o] = lv[0][o]+lv[1][o]+lv[2][o]+lv[3][o];
  }
}

// Kernel 6: exclusive scan of chunk totals; also writes grand-total row PU[NN]/PV[NN]
__global__ __launch_bounds__(128) void k_scanT(
    const float* __restrict__ TU, const float* __restrict__ TV,
    float* __restrict__ baseU, float* __restrict__ baseV,
    float* __restrict__ PU, float* __restrict__ PV)
{
  const int tid = threadIdx.x;
  if (tid < 64) {
    float run = 0.f;
    for (int b = 0; b < 32; ++b) { baseU[b*64+tid] = run; run += TU[b*64+tid]; }
    PU[(size_t)NN*OO + tid] = run;
  } else {
    const int o = tid - 64;
    float run = 0.f;
    for (int b = 0; b < 32; ++b) { baseV[b*64+o] = run; run += TV[b*64+o]; }
    PV[(size_t)NN*OO + o] = run;
  }
}

// Kernel 7: within-chunk serial exclusive scan -> full prefix tables PU/PV [NN+1][OO]
__global__ __launch_bounds__(64) void k_scanApply(
    const float* __restrict__ u_s, const float* __restrict__ v_s,
    const float* __restrict__ baseU, const float* __restrict__ baseV,
    float* __restrict__ PU, float* __restrict__ PV)
{
  const int b = blockIdx.x, o = threadIdx.x;
  if (blockIdx.y == 0) {
    float run = baseU[b*64+o];
    for (int k = 0; k < 256; ++k) {
      const size_t kk = (size_t)(b*256+k);
      PU[kk*OO+o] = run;
      run += u_s[kk*OO+o];
    }
  } else {
    float run = baseV[b*64+o];
    for (int k = 0; k < 256; ++k) {
      const size_t kk = (size_t)(b*256+k);
      PV[kk*OO+o] = run;
      run += v_s[kk*OO+o];
    }
  }
}

// Kernel 8: per (i,o): binary search k_i = #{f2 < -f1[i]}, combine prefix sums, ELU
__global__ __launch_bounds__(256) void k_final(
    const float* __restrict__ f1, const float* __restrict__ E1,
    const float* __restrict__ E1s, const float* __restrict__ f2s,
    const float* __restrict__ PU, const float* __restrict__ PV,
    float* __restrict__ out)
{
  __shared__ float sf[NN];
  const int tid = threadIdx.x;
  for (int q = tid; q < NN/4; q += 256)
    ((float4*)sf)[q] = ((const float4*)f2s)[q];
  __syncthreads();
  const int i = blockIdx.x*4 + (tid >> 6);
  const int o = tid & 63;
  const float t = -f1[i];
  int lo = 0, hi = NN;
  while (lo < hi) { const int mid = (lo+hi) >> 1; if (sf[mid] < t) lo = mid+1; else hi = mid; }
  const size_t k = (size_t)lo;
  const float utot = PU[(size_t)NN*OO + o];
  const float ret = E1[i]*(utot - PU[k*OO+o]) + E1s[i]*PV[k*OO+o];
  out[(size_t)i*OO + o] = ret > 0.f ? ret : expm1f(ret);
}

extern "C" void kernel_launch(void* const* d_in, const int* in_sizes, int n_in,
                              void* d_out, int out_size, void* d_ws, size_t ws_size,
                              hipStream_t stream)
{
  (void)in_sizes; (void)n_in; (void)out_size; (void)ws_size;
  const float* x   = (const float*)d_in[0];
  const float* W1  = (const float*)d_in[1];
  const float* b1  = (const float*)d_in[2];
  const float* a1  = (const float*)d_in[3];
  const float* ba1 = (const float*)d_in[4];
  const float* a2  = (const float*)d_in[5];
  const float* ba2 = (const float*)d_in[6];
  float* out = (float*)d_out;

  float* w = (float*)d_ws;
  size_t off = 0;
  auto alloc = [&](size_t n) { float* p = w + off; off += (n + 63) & ~(size_t)63; return p; };
  float* seq  = alloc((size_t)NN*OO);
  float* f1   = alloc(NN);
  float* f2   = alloc(NN);
  float* E1   = alloc(NN);
  float* E1s  = alloc(NN);
  float* eF2  = alloc(NN);
  float* eF2s = alloc(NN);
  float* pA   = alloc((size_t)NCH*NN);
  float* pB   = alloc((size_t)NCH*NN);
  float* pR   = alloc((size_t)NCH*NN);
  float* Bfac = alloc(NN);
  float* Efac = alloc(NN);
  float* f2s  = alloc(NN);
  int*   rank = (int*)alloc(NN);
  float* u_s  = alloc((size_t)NN*OO);
  float* v_s  = alloc((size_t)NN*OO);
  float* TU   = alloc(32*64);
  float* TV   = alloc(32*64);
  float* baseU= alloc(32*64);
  float* baseV= alloc(32*64);
  float* PU   = alloc((size_t)(NN+1)*OO);
  float* PV   = alloc((size_t)(NN+1)*OO);

  k_seq<<<512, 256, 0, stream>>>(x, W1, b1, a1, ba1, a2, ba2,
                                 seq, f1, f2, E1, E1s, eF2, eF2s);
  k_part<<<1024, 256, 0, stream>>>(f1, f2, E1, E1s, pA, pB, pR);
  k_reduce<<<32, 256, 0, stream>>>(pA, pB, pR, f2, eF2, eF2s, Bfac, Efac, rank, f2s);
  k_scatter<<<2048, 256, 0, stream>>>(seq, rank, Bfac, Efac, u_s, v_s);
  k_sumchunk<<<32, 256, 0, stream>>>(u_s, v_s, TU, TV);
  k_scanT<<<1, 128, 0, stream>>>(TU, TV, baseU, baseV, PU, PV);
  k_scanApply<<<dim3(32,2), 64, 0, stream>>>(u_s, v_s, baseU, baseV, PU, PV);
  k_final<<<2048, 256, 0, stream>>>(f1, E1, E1s, f2s, PU, PV, out);
}

// Round 2
// 115.304 us; speedup vs baseline: 1.1673x; 1.1673x over previous
//
#include <hip/hip_runtime.h>
#include <hip/hip_bf16.h>
#include <math.h>

#define NN 8192
#define CC 256
#define OO 64
#define NCH 32
#define SCH 64      // scan chunks
#define SROWS 128   // rows per scan chunk

// Kernel 0: transpose W1[64][256] -> W1T[256][64]
__global__ __launch_bounds__(256) void k_w1t(
    const float* __restrict__ W1, float* __restrict__ W1T)
{
  const int idx = blockIdx.x*256 + threadIdx.x;   // 64 blocks cover 16384
  const int o = idx >> 8, c = idx & 255;
  W1T[c*OO + o] = W1[idx];
}

// Kernel 1: seq[i][o] = x[i,:]@W1T[:,o] + b1[o] — coalesced W1T reads, 4 FMA chains/thread
__global__ __launch_bounds__(256) void k_seq2(
    const float* __restrict__ x, const float* __restrict__ W1T,
    const float* __restrict__ b1, float* __restrict__ seq)
{
  const int o  = threadIdx.x & 63;
  const int wq = threadIdx.x >> 6;          // 0..3
  const int i0 = blockIdx.x*8 + wq*2;
  const int i1 = i0 + 1;
  const float* xr0 = x + (size_t)i0*CC;
  const float* xr1 = x + (size_t)i1*CC;
  float a00 = 0.f, a01 = 0.f, a10 = 0.f, a11 = 0.f;
  for (int c = 0; c < CC; c += 8) {
    const float4 xa0 = *(const float4*)(xr0 + c);
    const float4 xa1 = *(const float4*)(xr0 + c + 4);
    const float4 xb0 = *(const float4*)(xr1 + c);
    const float4 xb1 = *(const float4*)(xr1 + c + 4);
    const float w0 = W1T[(c+0)*OO + o];
    const float w1 = W1T[(c+1)*OO + o];
    const float w2 = W1T[(c+2)*OO + o];
    const float w3 = W1T[(c+3)*OO + o];
    const float w4 = W1T[(c+4)*OO + o];
    const float w5 = W1T[(c+5)*OO + o];
    const float w6 = W1T[(c+6)*OO + o];
    const float w7 = W1T[(c+7)*OO + o];
    a00 = fmaf(xa0.x, w0, a00); a00 = fmaf(xa0.y, w1, a00);
    a00 = fmaf(xa0.z, w2, a00); a00 = fmaf(xa0.w, w3, a00);
    a01 = fmaf(xa1.x, w4, a01); a01 = fmaf(xa1.y, w5, a01);
    a01 = fmaf(xa1.z, w6, a01); a01 = fmaf(xa1.w, w7, a01);
    a10 = fmaf(xb0.x, w0, a10); a10 = fmaf(xb0.y, w1, a10);
    a10 = fmaf(xb0.z, w2, a10); a10 = fmaf(xb0.w, w3, a10);
    a11 = fmaf(xb1.x, w4, a11); a11 = fmaf(xb1.y, w5, a11);
    a11 = fmaf(xb1.z, w6, a11); a11 = fmaf(xb1.w, w7, a11);
  }
  const float bb = b1[o];
  seq[(size_t)i0*OO + o] = a00 + a01 + bb;
  seq[(size_t)i1*OO + o] = a10 + a11 + bb;
}

// Kernel 2: f1/f2 + exp tables via per-wave shuffle reduce (1 row per wave)
__global__ __launch_bounds__(256) void k_f(
    const float* __restrict__ seq, const float* __restrict__ a1,
    const float* __restrict__ ba1, const float* __restrict__ a2,
    const float* __restrict__ ba2,
    float* __restrict__ f1, float* __restrict__ f2,
    float* __restrict__ E1, float* __restrict__ E1s,
    float* __restrict__ eF2, float* __restrict__ eF2s)
{
  const int lane = threadIdx.x & 63;
  const int wv = threadIdx.x >> 6;
  const int i = blockIdx.x*4 + wv;
  const float s = seq[(size_t)i*OO + lane];
  float p1 = s * a1[lane];
  float p2 = s * a2[lane];
  for (int d = 32; d; d >>= 1) {
    p1 += __shfl_xor(p1, d, 64);
    p2 += __shfl_xor(p2, d, 64);
  }
  if (lane == 0) {
    const float t1 = p1 + ba1[0], t2 = p2 + ba2[0];
    f1[i] = t1; E1[i] = expf(t1); E1s[i] = expf(0.01f*t1);
    f2[i] = t2; eF2[i] = expf(t2); eF2s[i] = expf(0.01f*t2);
  }
}

// Kernel 3: per j, over one i-chunk: partial softmax-denominator terms + partial rank of f2[j]
__global__ __launch_bounds__(256) void k_part(
    const float* __restrict__ f1, const float* __restrict__ f2,
    const float* __restrict__ E1, const float* __restrict__ E1s,
    float* __restrict__ pA, float* __restrict__ pB, float* __restrict__ pR)
{
  const int ch = blockIdx.x >> 5;        // 32 i-chunks of 256
  const int jb = blockIdx.x & 31;        // 32 j-blocks of 256
  const int j = jb*256 + threadIdx.x;
  __shared__ float sf1[256], sa[256], sb[256], sf2c[256];
  const int ib = ch*256;
  sf1[threadIdx.x]  = f1[ib + threadIdx.x];
  sa[threadIdx.x]   = E1[ib + threadIdx.x];
  sb[threadIdx.x]   = E1s[ib + threadIdx.x];
  sf2c[threadIdx.x] = f2[ib + threadIdx.x];
  __syncthreads();
  const float myf2 = f2[j];
  const float t = -myf2;
  float accA = 0.f, accB = 0.f, cnt = 0.f;
#pragma unroll 4
  for (int ii = 0; ii < 256; ++ii) {
    const bool ge = sf1[ii] >= t;          // f1[i]+f2[j] >= 0
    accA += ge ? sa[ii] : 0.f;
    accB += ge ? 0.f : sb[ii];
    const float w = sf2c[ii];
    cnt += (w < myf2 || (w == myf2 && (ib+ii) < j)) ? 1.f : 0.f;
  }
  pA[ch*NN + j] = accA;
  pB[ch*NN + j] = accB;
  pR[ch*NN + j] = cnt;
}

// Kernel 4: reduce partials -> D_j, scale factors, rank; scatter sorted f2
__global__ __launch_bounds__(256) void k_reduce(
    const float* __restrict__ pA, const float* __restrict__ pB,
    const float* __restrict__ pR, const float* __restrict__ f2,
    const float* __restrict__ eF2, const float* __restrict__ eF2s,
    float* __restrict__ Bfac, float* __restrict__ Efac,
    int* __restrict__ rank, float* __restrict__ f2s)
{
  const int j = blockIdx.x*256 + threadIdx.x;
  float A = 0.f, Bv = 0.f, R = 0.f;
  for (int ch = 0; ch < NCH; ++ch) {
    A  += pA[ch*NN + j];
    Bv += pB[ch*NN + j];
    R  += pR[ch*NN + j];
  }
  const float D = A*eF2[j] + Bv*eF2s[j];
  Bfac[j] = eF2[j]/D;
  Efac[j] = eF2s[j]/D;
  const int r = (int)(R + 0.5f);
  rank[j] = r;
  f2s[r] = f2[j];
}

// Kernel 5: scatter u,v into sorted-by-f2 order
__global__ __launch_bounds__(256) void k_scatter(
    const float* __restrict__ seq, const int* __restrict__ rank,
    const float* __restrict__ Bfac, const float* __restrict__ Efac,
    float* __restrict__ u_s, float* __restrict__ v_s)
{
  const int gid = blockIdx.x*256 + threadIdx.x;
  const int j = gid >> 6, o = gid & 63;
  const int r = rank[j];
  const float s = seq[(size_t)j*OO + o];
  u_s[(size_t)r*OO + o] = Bfac[j]*s;
  v_s[(size_t)r*OO + o] = Efac[j]*s;
}

// Kernel 6: per-chunk column totals (chunk = SROWS sorted rows)
__global__ __launch_bounds__(256) void k_sumchunk(
    const float* __restrict__ u_s, const float* __restrict__ v_s,
    float* __restrict__ TU, float* __restrict__ TV)
{
  const int b = blockIdx.x, tid = threadIdx.x;
  const int ks = tid >> 6, o = tid & 63;
  float su = 0.f, sv = 0.f;
  for (int m = 0; m < SROWS/4; ++m) {
    const size_t idx = ((size_t)(b*SROWS + ks*(SROWS/4) + m))*OO + o;
    su += u_s[idx]; sv += v_s[idx];
  }
  __shared__ float lu[4][64], lv[4][64];
  lu[ks][o] = su; lv[ks][o] = sv;
  __syncthreads();
  if (ks == 0) {
    TU[b*64+o] = lu[0][o]+lu[1][o]+lu[2][o]+lu[3][o];
    TV[b*64+o] = lv[0][o]+lv[1][o]+lv[2][o]+lv[3][o];
  }
}

// Kernel 7: exclusive scan of chunk totals; also writes grand-total row PU[NN]/PV[NN]
__global__ __launch_bounds__(128) void k_scanT(
    const float* __restrict__ TU, const float* __restrict__ TV,
    float* __restrict__ baseU, float* __restrict__ baseV,
    float* __restrict__ PU, float* __restrict__ PV)
{
  const int tid = threadIdx.x;
  if (tid < 64) {
    float run = 0.f;
    for (int b = 0; b < SCH; ++b) { baseU[b*64+tid] = run; run += TU[b*64+tid]; }
    PU[(size_t)NN*OO + tid] = run;
  } else {
    const int o = tid - 64;
    float run = 0.f;
    for (int b = 0; b < SCH; ++b) { baseV[b*64+o] = run; run += TV[b*64+o]; }
    PV[(size_t)NN*OO + o] = run;
  }
}

// Kernel 8: within-chunk serial exclusive scan -> full prefix tables PU/PV [NN+1][OO]
__global__ __launch_bounds__(64) void k_scanApply(
    const float* __restrict__ u_s, const float* __restrict__ v_s,
    const float* __restrict__ baseU, const float* __restrict__ baseV,
    float* __restrict__ PU, float* __restrict__ PV)
{
  const int b = blockIdx.x, o = threadIdx.x;
  if (blockIdx.y == 0) {
    float run = baseU[b*64+o];
    for (int k = 0; k < SROWS; ++k) {
      const size_t kk = (size_t)(b*SROWS+k);
      PU[kk*OO+o] = run;
      run += u_s[kk*OO+o];
    }
  } else {
    float run = baseV[b*64+o];
    for (int k = 0; k < SROWS; ++k) {
      const size_t kk = (size_t)(b*SROWS+k);
      PV[kk*OO+o] = run;
      run += v_s[kk*OO+o];
    }
  }
}

// Kernel 9: per (i,o): binary search k_i = #{f2 < -f1[i]}, combine prefix sums, ELU
__global__ __launch_bounds__(256) void k_final(
    const float* __restrict__ f1, const float* __restrict__ E1,
    const float* __restrict__ E1s, const float* __restrict__ f2s,
    const float* __restrict__ PU, const float* __restrict__ PV,
    float* __restrict__ out)
{
  __shared__ float sf[NN];
  const int tid = threadIdx.x;
  for (int q = tid; q < NN/4; q += 256)
    ((float4*)sf)[q] = ((const float4*)f2s)[q];
  __syncthreads();
  const int i = blockIdx.x*4 + (tid >> 6);
  const int o = tid & 63;
  const float t = -f1[i];
  int lo = 0, hi = NN;
  while (lo < hi) { const int mid = (lo+hi) >> 1; if (sf[mid] < t) lo = mid+1; else hi = mid; }
  const size_t k = (size_t)lo;
  const float utot = PU[(size_t)NN*OO + o];
  const float ret = E1[i]*(utot - PU[k*OO+o]) + E1s[i]*PV[k*OO+o];
  out[(size_t)i*OO + o] = ret > 0.f ? ret : expm1f(ret);
}

extern "C" void kernel_launch(void* const* d_in, const int* in_sizes, int n_in,
                              void* d_out, int out_size, void* d_ws, size_t ws_size,
                              hipStream_t stream)
{
  (void)in_sizes; (void)n_in; (void)out_size; (void)ws_size;
  const float* x   = (const float*)d_in[0];
  const float* W1  = (const float*)d_in[1];
  const float* b1  = (const float*)d_in[2];
  const float* a1  = (const float*)d_in[3];
  const float* ba1 = (const float*)d_in[4];
  const float* a2  = (const float*)d_in[5];
  const float* ba2 = (const float*)d_in[6];
  float* out = (float*)d_out;

  float* w = (float*)d_ws;
  size_t off = 0;
  auto alloc = [&](size_t n) { float* p = w + off; off += (n + 63) & ~(size_t)63; return p; };
  float* W1T  = alloc((size_t)CC*OO);
  float* seq  = alloc((size_t)NN*OO);
  float* f1   = alloc(NN);
  float* f2   = alloc(NN);
  float* E1   = alloc(NN);
  float* E1s  = alloc(NN);
  float* eF2  = alloc(NN);
  float* eF2s = alloc(NN);
  float* pA   = alloc((size_t)NCH*NN);
  float* pB   = alloc((size_t)NCH*NN);
  float* pR   = alloc((size_t)NCH*NN);
  float* Bfac = alloc(NN);
  float* Efac = alloc(NN);
  float* f2s  = alloc(NN);
  int*   rank = (int*)alloc(NN);
  float* u_s  = alloc((size_t)NN*OO);
  float* v_s  = alloc((size_t)NN*OO);
  float* TU   = alloc(SCH*64);
  float* TV   = alloc(SCH*64);
  float* baseU= alloc(SCH*64);
  float* baseV= alloc(SCH*64);
  float* PU   = alloc((size_t)(NN+1)*OO);
  float* PV   = alloc((size_t)(NN+1)*OO);

  k_w1t<<<64, 256, 0, stream>>>(W1, W1T);
  k_seq2<<<1024, 256, 0, stream>>>(x, W1T, b1, seq);
  k_f<<<2048, 256, 0, stream>>>(seq, a1, ba1, a2, ba2, f1, f2, E1, E1s, eF2, eF2s);
  k_part<<<1024, 256, 0, stream>>>(f1, f2, E1, E1s, pA, pB, pR);
  k_reduce<<<32, 256, 0, stream>>>(pA, pB, pR, f2, eF2, eF2s, Bfac, Efac, rank, f2s);
  k_scatter<<<2048, 256, 0, stream>>>(seq, rank, Bfac, Efac, u_s, v_s);
  k_sumchunk<<<SCH, 256, 0, stream>>>(u_s, v_s, TU, TV);
  k_scanT<<<1, 128, 0, stream>>>(TU, TV, baseU, baseV, PU, PV);
  k_scanApply<<<dim3(SCH,2), 64, 0, stream>>>(u_s, v_s, baseU, baseV, PU, PV);
  k_final<<<2048, 256, 0, stream>>>(f1, E1, E1s, f2s, PU, PV, out);
}

// Round 3
// 87.899 us; speedup vs baseline: 1.5312x; 1.3118x over previous
//
#include <hip/hip_runtime.h>
#include <hip/hip_bf16.h>
#include <math.h>

#define NN 8192
#define CC 256
#define OO 64
#define RCH 512    // rank-count chunk size
#define SCH 128    // scan chunks
#define SROWS 64   // rows per scan chunk

// Kernel 0: transpose W1[64][256] -> W1T[256][64]
__global__ __launch_bounds__(256) void k_w1t(
    const float* __restrict__ W1, float* __restrict__ W1T)
{
  const int idx = blockIdx.x*256 + threadIdx.x;
  const int o = idx >> 8, c = idx & 255;
  W1T[c*OO + o] = W1[idx];
}

// Kernel 1: GEMM + fused f1/f2 row-reductions + exp tables + sortable keys
__global__ __launch_bounds__(256) void k_seq2(
    const float* __restrict__ x, const float* __restrict__ W1T,
    const float* __restrict__ b1, const float* __restrict__ a1,
    const float* __restrict__ ba1, const float* __restrict__ a2,
    const float* __restrict__ ba2,
    float* __restrict__ seq,
    float* __restrict__ f1, float* __restrict__ f2,
    float* __restrict__ E1, float* __restrict__ E1s,
    float* __restrict__ eF2, float* __restrict__ eF2s,
    unsigned long long* __restrict__ keys /* [2][NN] */)
{
  const int o  = threadIdx.x & 63;
  const int wq = threadIdx.x >> 6;
  const int i0 = blockIdx.x*8 + wq*2;
  const int i1 = i0 + 1;
  const float* xr0 = x + (size_t)i0*CC;
  const float* xr1 = x + (size_t)i1*CC;
  float a00 = 0.f, a01 = 0.f, a10 = 0.f, a11 = 0.f;
  for (int c = 0; c < CC; c += 8) {
    const float4 xa0 = *(const float4*)(xr0 + c);
    const float4 xa1 = *(const float4*)(xr0 + c + 4);
    const float4 xb0 = *(const float4*)(xr1 + c);
    const float4 xb1 = *(const float4*)(xr1 + c + 4);
    const float w0 = W1T[(c+0)*OO + o];
    const float w1 = W1T[(c+1)*OO + o];
    const float w2 = W1T[(c+2)*OO + o];
    const float w3 = W1T[(c+3)*OO + o];
    const float w4 = W1T[(c+4)*OO + o];
    const float w5 = W1T[(c+5)*OO + o];
    const float w6 = W1T[(c+6)*OO + o];
    const float w7 = W1T[(c+7)*OO + o];
    a00 = fmaf(xa0.x, w0, a00); a00 = fmaf(xa0.y, w1, a00);
    a00 = fmaf(xa0.z, w2, a00); a00 = fmaf(xa0.w, w3, a00);
    a01 = fmaf(xa1.x, w4, a01); a01 = fmaf(xa1.y, w5, a01);
    a01 = fmaf(xa1.z, w6, a01); a01 = fmaf(xa1.w, w7, a01);
    a10 = fmaf(xb0.x, w0, a10); a10 = fmaf(xb0.y, w1, a10);
    a10 = fmaf(xb0.z, w2, a10); a10 = fmaf(xb0.w, w3, a10);
    a11 = fmaf(xb1.x, w4, a11); a11 = fmaf(xb1.y, w5, a11);
    a11 = fmaf(xb1.z, w6, a11); a11 = fmaf(xb1.w, w7, a11);
  }
  const float bb = b1[o];
  const float v0 = a00 + a01 + bb;
  const float v1 = a10 + a11 + bb;
  seq[(size_t)i0*OO + o] = v0;
  seq[(size_t)i1*OO + o] = v1;
  const float A1 = a1[o], A2 = a2[o];
  float p10 = v0*A1, p20 = v0*A2, p11 = v1*A1, p21 = v1*A2;
  for (int d = 32; d; d >>= 1) {
    p10 += __shfl_xor(p10, d, 64);
    p20 += __shfl_xor(p20, d, 64);
    p11 += __shfl_xor(p11, d, 64);
    p21 += __shfl_xor(p21, d, 64);
  }
  if (o == 0) {
    const float bba1 = ba1[0], bba2 = ba2[0];
    const float t1a = p10 + bba1, t2a = p20 + bba2;
    const float t1b = p11 + bba1, t2b = p21 + bba2;
    f1[i0] = t1a; E1[i0] = expf(t1a); E1s[i0] = expf(0.01f*t1a);
    f2[i0] = t2a; eF2[i0] = expf(t2a); eF2s[i0] = expf(0.01f*t2a);
    f1[i1] = t1b; E1[i1] = expf(t1b); E1s[i1] = expf(0.01f*t1b);
    f2[i1] = t2b; eF2[i1] = expf(t2b); eF2s[i1] = expf(0.01f*t2b);
    unsigned u;
    u = __float_as_uint(t1a); u = (u & 0x80000000u) ? ~u : (u | 0x80000000u);
    keys[i0] = ((unsigned long long)u << 32) | (unsigned)i0;
    u = __float_as_uint(t1b); u = (u & 0x80000000u) ? ~u : (u | 0x80000000u);
    keys[i1] = ((unsigned long long)u << 32) | (unsigned)i1;
    u = __float_as_uint(t2a); u = (u & 0x80000000u) ? ~u : (u | 0x80000000u);
    keys[NN + i0] = ((unsigned long long)u << 32) | (unsigned)i0;
    u = __float_as_uint(t2b); u = (u & 0x80000000u) ? ~u : (u | 0x80000000u);
    keys[NN + i1] = ((unsigned long long)u << 32) | (unsigned)i1;
  }
}

// Kernel 2: brute-force rank counting on u64 keys (both arrays), atomic accumulate
__global__ __launch_bounds__(256) void k_rank(
    const unsigned long long* __restrict__ keys, int* __restrict__ rank)
{
  const int arr = blockIdx.z;
  const int ch  = blockIdx.y;
  const int j = blockIdx.x*256 + threadIdx.x;
  __shared__ unsigned long long sk[RCH];
  const unsigned long long* kb = keys + (size_t)arr*NN;
  for (int q = threadIdx.x; q < RCH; q += 256)
    sk[q] = kb[ch*RCH + q];
  __syncthreads();
  const unsigned long long my = kb[j];
  int cnt = 0;
#pragma unroll 8
  for (int ii = 0; ii < RCH; ++ii)
    cnt += (sk[ii] < my) ? 1 : 0;
  atomicAdd(&rank[arr*NN + j], cnt);
}

// Kernel 3: scatter f1-side tables into f1-sorted order; f2 into f2-sorted order
__global__ __launch_bounds__(256) void k_scat1(
    const int* __restrict__ rank, const float* __restrict__ f1,
    const float* __restrict__ E1, const float* __restrict__ E1s,
    const float* __restrict__ f2,
    float* __restrict__ s1, float* __restrict__ se1,
    float* __restrict__ se1s, float* __restrict__ f2s)
{
  const int i = blockIdx.x*256 + threadIdx.x;
  const int r1 = rank[i];
  s1[r1] = f1[i]; se1[r1] = E1[i]; se1s[r1] = E1s[i];
  const int r2 = rank[NN + i];
  f2s[r2] = f2[i];
}

// Kernel 4: single-block exclusive scans of se1, se1s -> PreE1[NN+1], PreE1s[NN+1]
__global__ __launch_bounds__(256) void k_scanE(
    const float* __restrict__ se1, const float* __restrict__ se1s,
    float* __restrict__ PreE1, float* __restrict__ PreE1s)
{
  __shared__ float part[256];
  const int t = threadIdx.x;
  for (int pass = 0; pass < 2; ++pass) {
    const float* src = pass ? se1s : se1;
    float* dst = pass ? PreE1s : PreE1;
    float loc[32];
    float s = 0.f;
#pragma unroll
    for (int q = 0; q < 32; ++q) { loc[q] = src[t*32 + q]; s += loc[q]; }
    part[t] = s;
    __syncthreads();
    for (int d = 1; d < 256; d <<= 1) {
      float v = (t >= d) ? part[t-d] : 0.f;
      __syncthreads();
      part[t] += v;
      __syncthreads();
    }
    float run = part[t] - s;   // exclusive base
#pragma unroll
    for (int q = 0; q < 32; ++q) { dst[t*32 + q] = run; run += loc[q]; }
    if (t == 255) dst[NN] = run;
    __syncthreads();
  }
}

// Kernel 5: per j, binary search -f2[j] in sorted f1 -> D_j -> scale factors
__global__ __launch_bounds__(256) void k_D(
    const float* __restrict__ s1, const float* __restrict__ PreE1,
    const float* __restrict__ PreE1s, const float* __restrict__ f2,
    const float* __restrict__ eF2, const float* __restrict__ eF2s,
    float* __restrict__ Bfac, float* __restrict__ Efac)
{
  __shared__ float sf[NN];
  for (int q = threadIdx.x; q < NN/4; q += 256)
    ((float4*)sf)[q] = ((const float4*)s1)[q];
  __syncthreads();
  const int j = blockIdx.x*256 + threadIdx.x;
  const float t = -f2[j];
  int lo = 0, hi = NN;
  while (lo < hi) { const int mid = (lo+hi) >> 1; if (sf[mid] < t) lo = mid+1; else hi = mid; }
  const float T1 = PreE1[NN];
  const float A  = T1 - PreE1[lo];
  const float Bv = PreE1s[lo];
  const float D = A*eF2[j] + Bv*eF2s[j];
  Bfac[j] = eF2[j]/D;
  Efac[j] = eF2s[j]/D;
}

// Kernel 6: scatter u,v into sorted-by-f2 order
__global__ __launch_bounds__(256) void k_scatter(
    const float* __restrict__ seq, const int* __restrict__ rank,
    const float* __restrict__ Bfac, const float* __restrict__ Efac,
    float* __restrict__ u_s, float* __restrict__ v_s)
{
  const int gid = blockIdx.x*256 + threadIdx.x;
  const int j = gid >> 6, o = gid & 63;
  const int r = rank[NN + j];
  const float s = seq[(size_t)j*OO + o];
  u_s[(size_t)r*OO + o] = Bfac[j]*s;
  v_s[(size_t)r*OO + o] = Efac[j]*s;
}

// Kernel 7: per-chunk column totals (chunk = SROWS sorted rows)
__global__ __launch_bounds__(256) void k_sumchunk(
    const float* __restrict__ u_s, const float* __restrict__ v_s,
    float* __restrict__ TU, float* __restrict__ TV)
{
  const int b = blockIdx.x, tid = threadIdx.x;
  const int ks = tid >> 6, o = tid & 63;
  float su = 0.f, sv = 0.f;
#pragma unroll
  for (int m = 0; m < SROWS/4; ++m) {
    const size_t idx = ((size_t)(b*SROWS + ks*(SROWS/4) + m))*OO + o;
    su += u_s[idx]; sv += v_s[idx];
  }
  __shared__ float lu[4][64], lv[4][64];
  lu[ks][o] = su; lv[ks][o] = sv;
  __syncthreads();
  if (ks == 0) {
    TU[b*64+o] = lu[0][o]+lu[1][o]+lu[2][o]+lu[3][o];
    TV[b*64+o] = lv[0][o]+lv[1][o]+lv[2][o]+lv[3][o];
  }
}

// Kernel 8: exclusive scan of chunk totals; writes grand-total row PU[NN]/PV[NN]
__global__ __launch_bounds__(128) void k_scanT(
    const float* __restrict__ TU, const float* __restrict__ TV,
    float* __restrict__ baseU, float* __restrict__ baseV,
    float* __restrict__ PU, float* __restrict__ PV)
{
  const int tid = threadIdx.x;
  const float* src = (tid < 64) ? TU : TV;
  float* dstb = (tid < 64) ? baseU : baseV;
  float* dstP = (tid < 64) ? PU : PV;
  const int o = tid & 63;
  float run = 0.f;
#pragma unroll 8
  for (int b = 0; b < SCH; ++b) { dstb[b*64+o] = run; run += src[b*64+o]; }
  dstP[(size_t)NN*OO + o] = run;
}

// Kernel 9: within-chunk serial exclusive scan -> full prefix tables PU/PV [NN+1][OO]
__global__ __launch_bounds__(64) void k_scanApply(
    const float* __restrict__ u_s, const float* __restrict__ v_s,
    const float* __restrict__ baseU, const float* __restrict__ baseV,
    float* __restrict__ PU, float* __restrict__ PV)
{
  const int b = blockIdx.x, o = threadIdx.x;
  const float* src = blockIdx.y ? v_s : u_s;
  const float* bas = blockIdx.y ? baseV : baseU;
  float* dst = blockIdx.y ? PV : PU;
  float run = bas[b*64+o];
#pragma unroll 4
  for (int k = 0; k < SROWS; ++k) {
    const size_t kk = (size_t)(b*SROWS+k);
    dst[kk*OO+o] = run;
    run += src[kk*OO+o];
  }
}

// Kernel 10: per (i,o): binary search k_i = #{f2 < -f1[i]}, combine prefix sums, ELU
__global__ __launch_bounds__(256) void k_final(
    const float* __restrict__ f1, const float* __restrict__ E1,
    const float* __restrict__ E1s, const float* __restrict__ f2s,
    const float* __restrict__ PU, const float* __restrict__ PV,
    float* __restrict__ out)
{
  __shared__ float sf[NN];
  const int tid = threadIdx.x;
  for (int q = tid; q < NN/4; q += 256)
    ((float4*)sf)[q] = ((const float4*)f2s)[q];
  __syncthreads();
  const int i = blockIdx.x*4 + (tid >> 6);
  const int o = tid & 63;
  const float t = -f1[i];
  int lo = 0, hi = NN;
  while (lo < hi) { const int mid = (lo+hi) >> 1; if (sf[mid] < t) lo = mid+1; else hi = mid; }
  const size_t k = (size_t)lo;
  const float utot = PU[(size_t)NN*OO + o];
  const float ret = E1[i]*(utot - PU[k*OO+o]) + E1s[i]*PV[k*OO+o];
  out[(size_t)i*OO + o] = ret > 0.f ? ret : expm1f(ret);
}

extern "C" void kernel_launch(void* const* d_in, const int* in_sizes, int n_in,
                              void* d_out, int out_size, void* d_ws, size_t ws_size,
                              hipStream_t stream)
{
  (void)in_sizes; (void)n_in; (void)out_size; (void)ws_size;
  const float* x   = (const float*)d_in[0];
  const float* W1  = (const float*)d_in[1];
  const float* b1  = (const float*)d_in[2];
  const float* a1  = (const float*)d_in[3];
  const float* ba1 = (const float*)d_in[4];
  const float* a2  = (const float*)d_in[5];
  const float* ba2 = (const float*)d_in[6];
  float* out = (float*)d_out;

  float* w = (float*)d_ws;
  size_t off = 0;
  auto alloc = [&](size_t n) { float* p = w + off; off += (n + 63) & ~(size_t)63; return p; };
  float* W1T  = alloc((size_t)CC*OO);
  float* seq  = alloc((size_t)NN*OO);
  float* f1   = alloc(NN);
  float* f2   = alloc(NN);
  float* E1   = alloc(NN);
  float* E1s  = alloc(NN);
  float* eF2  = alloc(NN);
  float* eF2s = alloc(NN);
  unsigned long long* keys = (unsigned long long*)alloc((size_t)2*NN*2);
  int*   rank = (int*)alloc((size_t)2*NN);
  float* s1   = alloc(NN);
  float* se1  = alloc(NN);
  float* se1s = alloc(NN);
  float* f2s  = alloc(NN);
  float* PreE1  = alloc(NN+64);
  float* PreE1s = alloc(NN+64);
  float* Bfac = alloc(NN);
  float* Efac = alloc(NN);
  float* u_s  = alloc((size_t)NN*OO);
  float* v_s  = alloc((size_t)NN*OO);
  float* TU   = alloc(SCH*64);
  float* TV   = alloc(SCH*64);
  float* baseU= alloc(SCH*64);
  float* baseV= alloc(SCH*64);
  float* PU   = alloc((size_t)(NN+1)*OO);
  float* PV   = alloc((size_t)(NN+1)*OO);

  k_w1t<<<64, 256, 0, stream>>>(W1, W1T);
  k_seq2<<<1024, 256, 0, stream>>>(x, W1T, b1, a1, ba1, a2, ba2,
                                   seq, f1, f2, E1, E1s, eF2, eF2s, keys);
  hipMemsetAsync(rank, 0, (size_t)2*NN*sizeof(int), stream);
  k_rank<<<dim3(32, NN/RCH, 2), 256, 0, stream>>>(keys, rank);
  k_scat1<<<32, 256, 0, stream>>>(rank, f1, E1, E1s, f2, s1, se1, se1s, f2s);
  k_scanE<<<1, 256, 0, stream>>>(se1, se1s, PreE1, PreE1s);
  k_D<<<32, 256, 0, stream>>>(s1, PreE1, PreE1s, f2, eF2, eF2s, Bfac, Efac);
  k_scatter<<<2048, 256, 0, stream>>>(seq, rank, Bfac, Efac, u_s, v_s);
  k_sumchunk<<<SCH, 256, 0, stream>>>(u_s, v_s, TU, TV);
  k_scanT<<<1, 128, 0, stream>>>(TU, TV, baseU, baseV, PU, PV);
  k_scanApply<<<dim3(SCH,2), 64, 0, stream>>>(u_s, v_s, baseU, baseV, PU, PV);
  k_final<<<2048, 256, 0, stream>>>(f1, E1, E1s, f2s, PU, PV, out);
}

// Round 4
// 87.151 us; speedup vs baseline: 1.5443x; 1.0086x over previous
//
#include <hip/hip_runtime.h>
#include <hip/hip_bf16.h>
#include <math.h>

#define NN 8192
#define CC 256
#define OO 64
#define RCH 512    // rank-count chunk size
#define NCHR 16    // NN/RCH
#define SCH 128    // scan chunks
#define SROWS 64   // rows per scan chunk

// Kernel 0: transpose W1[64][256] -> W1T[256][64]
__global__ __launch_bounds__(256) void k_w1t(
    const float* __restrict__ W1, float* __restrict__ W1T)
{
  const int idx = blockIdx.x*256 + threadIdx.x;
  const int o = idx >> 8, c = idx & 255;
  W1T[c*OO + o] = W1[idx];
}

// Kernel 1: GEMM + fused f1/f2 row-reductions + exp tables + sortable keys
__global__ __launch_bounds__(256) void k_seq2(
    const float* __restrict__ x, const float* __restrict__ W1T,
    const float* __restrict__ b1, const float* __restrict__ a1,
    const float* __restrict__ ba1, const float* __restrict__ a2,
    const float* __restrict__ ba2,
    float* __restrict__ seq,
    float* __restrict__ f1, float* __restrict__ f2,
    float* __restrict__ E1, float* __restrict__ E1s,
    float* __restrict__ eF2, float* __restrict__ eF2s,
    unsigned long long* __restrict__ keys /* [2][NN] */)
{
  const int o  = threadIdx.x & 63;
  const int wq = threadIdx.x >> 6;
  const int i0 = blockIdx.x*8 + wq*2;
  const int i1 = i0 + 1;
  const float* xr0 = x + (size_t)i0*CC;
  const float* xr1 = x + (size_t)i1*CC;
  float a00 = 0.f, a01 = 0.f, a10 = 0.f, a11 = 0.f;
  for (int c = 0; c < CC; c += 8) {
    const float4 xa0 = *(const float4*)(xr0 + c);
    const float4 xa1 = *(const float4*)(xr0 + c + 4);
    const float4 xb0 = *(const float4*)(xr1 + c);
    const float4 xb1 = *(const float4*)(xr1 + c + 4);
    const float w0 = W1T[(c+0)*OO + o];
    const float w1 = W1T[(c+1)*OO + o];
    const float w2 = W1T[(c+2)*OO + o];
    const float w3 = W1T[(c+3)*OO + o];
    const float w4 = W1T[(c+4)*OO + o];
    const float w5 = W1T[(c+5)*OO + o];
    const float w6 = W1T[(c+6)*OO + o];
    const float w7 = W1T[(c+7)*OO + o];
    a00 = fmaf(xa0.x, w0, a00); a00 = fmaf(xa0.y, w1, a00);
    a00 = fmaf(xa0.z, w2, a00); a00 = fmaf(xa0.w, w3, a00);
    a01 = fmaf(xa1.x, w4, a01); a01 = fmaf(xa1.y, w5, a01);
    a01 = fmaf(xa1.z, w6, a01); a01 = fmaf(xa1.w, w7, a01);
    a10 = fmaf(xb0.x, w0, a10); a10 = fmaf(xb0.y, w1, a10);
    a10 = fmaf(xb0.z, w2, a10); a10 = fmaf(xb0.w, w3, a10);
    a11 = fmaf(xb1.x, w4, a11); a11 = fmaf(xb1.y, w5, a11);
    a11 = fmaf(xb1.z, w6, a11); a11 = fmaf(xb1.w, w7, a11);
  }
  const float bb = b1[o];
  const float v0 = a00 + a01 + bb;
  const float v1 = a10 + a11 + bb;
  seq[(size_t)i0*OO + o] = v0;
  seq[(size_t)i1*OO + o] = v1;
  const float A1 = a1[o], A2 = a2[o];
  float p10 = v0*A1, p20 = v0*A2, p11 = v1*A1, p21 = v1*A2;
  for (int d = 32; d; d >>= 1) {
    p10 += __shfl_xor(p10, d, 64);
    p20 += __shfl_xor(p20, d, 64);
    p11 += __shfl_xor(p11, d, 64);
    p21 += __shfl_xor(p21, d, 64);
  }
  if (o == 0) {
    const float bba1 = ba1[0], bba2 = ba2[0];
    const float t1a = p10 + bba1, t2a = p20 + bba2;
    const float t1b = p11 + bba1, t2b = p21 + bba2;
    f1[i0] = t1a; E1[i0] = expf(t1a); E1s[i0] = expf(0.01f*t1a);
    f2[i0] = t2a; eF2[i0] = expf(t2a); eF2s[i0] = expf(0.01f*t2a);
    f1[i1] = t1b; E1[i1] = expf(t1b); E1s[i1] = expf(0.01f*t1b);
    f2[i1] = t2b; eF2[i1] = expf(t2b); eF2s[i1] = expf(0.01f*t2b);
    unsigned u;
    u = __float_as_uint(t1a); u = (u & 0x80000000u) ? ~u : (u | 0x80000000u);
    keys[i0] = ((unsigned long long)u << 32) | (unsigned)i0;
    u = __float_as_uint(t1b); u = (u & 0x80000000u) ? ~u : (u | 0x80000000u);
    keys[i1] = ((unsigned long long)u << 32) | (unsigned)i1;
    u = __float_as_uint(t2a); u = (u & 0x80000000u) ? ~u : (u | 0x80000000u);
    keys[NN + i0] = ((unsigned long long)u << 32) | (unsigned)i0;
    u = __float_as_uint(t2b); u = (u & 0x80000000u) ? ~u : (u | 0x80000000u);
    keys[NN + i1] = ((unsigned long long)u << 32) | (unsigned)i1;
  }
}

// Kernel 2: brute-force rank counting on u64 keys, per-chunk partial counts (no atomics)
__global__ __launch_bounds__(256) void k_rank(
    const unsigned long long* __restrict__ keys, int* __restrict__ pRank)
{
  const int arr = blockIdx.z;
  const int ch  = blockIdx.y;
  const int j = blockIdx.x*256 + threadIdx.x;
  __shared__ unsigned long long sk[RCH];
  const unsigned long long* kb = keys + (size_t)arr*NN;
  for (int q = threadIdx.x; q < RCH; q += 256)
    sk[q] = kb[ch*RCH + q];
  __syncthreads();
  const unsigned long long my = kb[j];
  int cnt = 0;
#pragma unroll 8
  for (int ii = 0; ii < RCH; ++ii)
    cnt += (sk[ii] < my) ? 1 : 0;
  pRank[(arr*NCHR + ch)*NN + j] = cnt;
}

// Kernel 3: sum rank partials; scatter f1-side tables f1-sorted; f2 f2-sorted; save rank2
__global__ __launch_bounds__(256) void k_scat1(
    const int* __restrict__ pRank, const float* __restrict__ f1,
    const float* __restrict__ E1, const float* __restrict__ E1s,
    const float* __restrict__ f2,
    float* __restrict__ s1, float* __restrict__ se1,
    float* __restrict__ se1s, float* __restrict__ f2s,
    int* __restrict__ rank2)
{
  const int i = blockIdx.x*256 + threadIdx.x;
  int r1 = 0, r2 = 0;
#pragma unroll
  for (int ch = 0; ch < NCHR; ++ch) {
    r1 += pRank[ch*NN + i];
    r2 += pRank[(NCHR + ch)*NN + i];
  }
  s1[r1] = f1[i]; se1[r1] = E1[i]; se1s[r1] = E1s[i];
  f2s[r2] = f2[i];
  rank2[i] = r2;
}

// Kernel 4: single-block exclusive scans of se1, se1s -> PreE1[NN+1], PreE1s[NN+1]
__global__ __launch_bounds__(256) void k_scanE(
    const float* __restrict__ se1, const float* __restrict__ se1s,
    float* __restrict__ PreE1, float* __restrict__ PreE1s)
{
  __shared__ float part[256];
  const int t = threadIdx.x;
  for (int pass = 0; pass < 2; ++pass) {
    const float* src = pass ? se1s : se1;
    float* dst = pass ? PreE1s : PreE1;
    float loc[32];
    float s = 0.f;
#pragma unroll
    for (int q = 0; q < 32; ++q) { loc[q] = src[t*32 + q]; s += loc[q]; }
    part[t] = s;
    __syncthreads();
    for (int d = 1; d < 256; d <<= 1) {
      float v = (t >= d) ? part[t-d] : 0.f;
      __syncthreads();
      part[t] += v;
      __syncthreads();
    }
    float run = part[t] - s;   // exclusive base
#pragma unroll
    for (int q = 0; q < 32; ++q) { dst[t*32 + q] = run; run += loc[q]; }
    if (t == 255) dst[NN] = run;
    __syncthreads();
  }
}

// Kernel 5: per j, binary search -f2[j] in sorted f1 (global, wave-uniform) -> D_j
__global__ __launch_bounds__(256) void k_D(
    const float* __restrict__ s1, const float* __restrict__ PreE1,
    const float* __restrict__ PreE1s, const float* __restrict__ f2,
    const float* __restrict__ eF2, const float* __restrict__ eF2s,
    float* __restrict__ Bfac, float* __restrict__ Efac)
{
  const int j = blockIdx.x*256 + threadIdx.x;
  const float t = -f2[j];
  int lo = 0, hi = NN;
  while (lo < hi) { const int mid = (lo+hi) >> 1; if (s1[mid] < t) lo = mid+1; else hi = mid; }
  const float T1 = PreE1[NN];
  const float A  = T1 - PreE1[lo];
  const float Bv = PreE1s[lo];
  const float D = A*eF2[j] + Bv*eF2s[j];
  Bfac[j] = eF2[j]/D;
  Efac[j] = eF2s[j]/D;
}

// Kernel 6: scatter u,v into sorted-by-f2 order
__global__ __launch_bounds__(256) void k_scatter(
    const float* __restrict__ seq, const int* __restrict__ rank2,
    const float* __restrict__ Bfac, const float* __restrict__ Efac,
    float* __restrict__ u_s, float* __restrict__ v_s)
{
  const int gid = blockIdx.x*256 + threadIdx.x;
  const int j = gid >> 6, o = gid & 63;
  const int r = rank2[j];
  const float s = seq[(size_t)j*OO + o];
  u_s[(size_t)r*OO + o] = Bfac[j]*s;
  v_s[(size_t)r*OO + o] = Efac[j]*s;
}

// Kernel 7: per-chunk column totals (chunk = SROWS sorted rows)
__global__ __launch_bounds__(256) void k_sumchunk(
    const float* __restrict__ u_s, const float* __restrict__ v_s,
    float* __restrict__ TU, float* __restrict__ TV)
{
  const int b = blockIdx.x, tid = threadIdx.x;
  const int ks = tid >> 6, o = tid & 63;
  float su = 0.f, sv = 0.f;
#pragma unroll
  for (int m = 0; m < SROWS/4; ++m) {
    const size_t idx = ((size_t)(b*SROWS + ks*(SROWS/4) + m))*OO + o;
    su += u_s[idx]; sv += v_s[idx];
  }
  __shared__ float lu[4][64], lv[4][64];
  lu[ks][o] = su; lv[ks][o] = sv;
  __syncthreads();
  if (ks == 0) {
    TU[b*64+o] = lu[0][o]+lu[1][o]+lu[2][o]+lu[3][o];
    TV[b*64+o] = lv[0][o]+lv[1][o]+lv[2][o]+lv[3][o];
  }
}

// Kernel 8: exclusive scan of chunk totals; writes grand-total row PU[NN]/PV[NN]
__global__ __launch_bounds__(128) void k_scanT(
    const float* __restrict__ TU, const float* __restrict__ TV,
    float* __restrict__ baseU, float* __restrict__ baseV,
    float* __restrict__ PU, float* __restrict__ PV)
{
  const int tid = threadIdx.x;
  const float* src = (tid < 64) ? TU : TV;
  float* dstb = (tid < 64) ? baseU : baseV;
  float* dstP = (tid < 64) ? PU : PV;
  const int o = tid & 63;
  float run = 0.f;
#pragma unroll 8
  for (int b = 0; b < SCH; ++b) { dstb[b*64+o] = run; run += src[b*64+o]; }
  dstP[(size_t)NN*OO + o] = run;
}

// Kernel 9: within-chunk serial exclusive scan -> full prefix tables PU/PV [NN+1][OO]
__global__ __launch_bounds__(64) void k_scanApply(
    const float* __restrict__ u_s, const float* __restrict__ v_s,
    const float* __restrict__ baseU, const float* __restrict__ baseV,
    float* __restrict__ PU, float* __restrict__ PV)
{
  const int b = blockIdx.x, o = threadIdx.x;
  const float* src = blockIdx.y ? v_s : u_s;
  const float* bas = blockIdx.y ? baseV : baseU;
  float* dst = blockIdx.y ? PV : PU;
  float run = bas[b*64+o];
#pragma unroll 4
  for (int k = 0; k < SROWS; ++k) {
    const size_t kk = (size_t)(b*SROWS+k);
    dst[kk*OO+o] = run;
    run += src[kk*OO+o];
  }
}

// Kernel 10: per (i,o): binary search k_i = #{f2 < -f1[i]} (global, wave-uniform), ELU
__global__ __launch_bounds__(256) void k_final(
    const float* __restrict__ f1, const float* __restrict__ E1,
    const float* __restrict__ E1s, const float* __restrict__ f2s,
    const float* __restrict__ PU, const float* __restrict__ PV,
    float* __restrict__ out)
{
  const int tid = threadIdx.x;
  const int i = blockIdx.x*4 + (tid >> 6);
  const int o = tid & 63;
  const float t = -f1[i];
  int lo = 0, hi = NN;
  while (lo < hi) { const int mid = (lo+hi) >> 1; if (f2s[mid] < t) lo = mid+1; else hi = mid; }
  const size_t k = (size_t)lo;
  const float utot = PU[(size_t)NN*OO + o];
  const float ret = E1[i]*(utot - PU[k*OO+o]) + E1s[i]*PV[k*OO+o];
  out[(size_t)i*OO + o] = ret > 0.f ? ret : expm1f(ret);
}

extern "C" void kernel_launch(void* const* d_in, const int* in_sizes, int n_in,
                              void* d_out, int out_size, void* d_ws, size_t ws_size,
                              hipStream_t stream)
{
  (void)in_sizes; (void)n_in; (void)out_size; (void)ws_size;
  const float* x   = (const float*)d_in[0];
  const float* W1  = (const float*)d_in[1];
  const float* b1  = (const float*)d_in[2];
  const float* a1  = (const float*)d_in[3];
  const float* ba1 = (const float*)d_in[4];
  const float* a2  = (const float*)d_in[5];
  const float* ba2 = (const float*)d_in[6];
  float* out = (float*)d_out;

  float* w = (float*)d_ws;
  size_t off = 0;
  auto alloc = [&](size_t n) { float* p = w + off; off += (n + 63) & ~(size_t)63; return p; };
  float* W1T  = alloc((size_t)CC*OO);
  float* seq  = alloc((size_t)NN*OO);
  float* f1   = alloc(NN);
  float* f2   = alloc(NN);
  float* E1   = alloc(NN);
  float* E1s  = alloc(NN);
  float* eF2  = alloc(NN);
  float* eF2s = alloc(NN);
  unsigned long long* keys = (unsigned long long*)alloc((size_t)4*NN);
  int*   pRank = (int*)alloc((size_t)2*NCHR*NN);
  int*   rank2 = (int*)alloc(NN);
  float* s1   = alloc(NN);
  float* se1  = alloc(NN);
  float* se1s = alloc(NN);
  float* f2s  = alloc(NN);
  float* PreE1  = alloc(NN+64);
  float* PreE1s = alloc(NN+64);
  float* Bfac = alloc(NN);
  float* Efac = alloc(NN);
  float* u_s  = alloc((size_t)NN*OO);
  float* v_s  = alloc((size_t)NN*OO);
  float* TU   = alloc(SCH*64);
  float* TV   = alloc(SCH*64);
  float* baseU= alloc(SCH*64);
  float* baseV= alloc(SCH*64);
  float* PU   = alloc((size_t)(NN+1)*OO);
  float* PV   = alloc((size_t)(NN+1)*OO);

  k_w1t<<<64, 256, 0, stream>>>(W1, W1T);
  k_seq2<<<1024, 256, 0, stream>>>(x, W1T, b1, a1, ba1, a2, ba2,
                                   seq, f1, f2, E1, E1s, eF2, eF2s, keys);
  k_rank<<<dim3(32, NCHR, 2), 256, 0, stream>>>(keys, pRank);
  k_scat1<<<32, 256, 0, stream>>>(pRank, f1, E1, E1s, f2, s1, se1, se1s, f2s, rank2);
  k_scanE<<<1, 256, 0, stream>>>(se1, se1s, PreE1, PreE1s);
  k_D<<<32, 256, 0, stream>>>(s1, PreE1, PreE1s, f2, eF2, eF2s, Bfac, Efac);
  k_scatter<<<2048, 256, 0, stream>>>(seq, rank2, Bfac, Efac, u_s, v_s);
  k_sumchunk<<<SCH, 256, 0, stream>>>(u_s, v_s, TU, TV);
  k_scanT<<<1, 128, 0, stream>>>(TU, TV, baseU, baseV, PU, PV);
  k_scanApply<<<dim3(SCH,2), 64, 0, stream>>>(u_s, v_s, baseU, baseV, PU, PV);
  k_final<<<2048, 256, 0, stream>>>(f1, E1, E1s, f2s, PU, PV, out);
}